// Round 21
// baseline (176.382 us; speedup 1.0000x reference)
//
#include <hip/hip_runtime.h>
#include <hip/hip_bf16.h>

// B=4 T=2048 C=1024 H=16 hd=64, causal MHSA, f32 in/out, bf16 MFMA internally.
// Pipeline: cvt(x) / transpose-cvt(w) -> GEMM1 (qkv) -> transpose V -> flash attn -> GEMM2.
// Attn: swapped-QK, static-max softmax, bf16-direct exp2, l via ones-MFMA (validated).
// R21: GEMM residency 2->3 blocks/CU done RIGHT: A 2-slot + B 2-slot = 48KB (BM=256),
//      launch_bounds(512,2) (R19's (512,6) capped VGPR at 40 -> spill); stage(t+1) at
//      loop top, drain vmcnt(0)+barrier at end (covered by 3 co-resident blocks --
//      same mechanism as the attn residency arc). GEMM2 BM=128: 32KB LDS.

typedef float f32x4 __attribute__((ext_vector_type(4)));
typedef float f32x16 __attribute__((ext_vector_type(16)));
typedef __bf16 bf16x8 __attribute__((ext_vector_type(8)));
typedef short short8v __attribute__((ext_vector_type(8)));
typedef unsigned int u32x4 __attribute__((ext_vector_type(4)));

__device__ __forceinline__ unsigned short f2bf(float f) {
  __hip_bfloat16 h = __float2bfloat16(f);
  return __builtin_bit_cast(unsigned short, h);
}

__device__ __forceinline__ void glds16(const void* g, void* l) {
  __builtin_amdgcn_global_load_lds((const __attribute__((address_space(1))) void*)g,
                                   (__attribute__((address_space(3))) void*)l, 16, 0, 0);
}

// ---------------- conversions ----------------
__global__ void cvt_f32_bf16_kernel(const float* __restrict__ in,
                                    unsigned short* __restrict__ out, int n) {
  int stride = gridDim.x * blockDim.x * 4;
  for (int i = (blockIdx.x * blockDim.x + threadIdx.x) * 4; i < n; i += stride) {
    float4 v = *(const float4*)(in + i);
    ushort4 o;
    o.x = f2bf(v.x); o.y = f2bf(v.y); o.z = f2bf(v.z); o.w = f2bf(v.w);
    *(ushort4*)(out + i) = o;
  }
}

// in: [K][N] f32 row-major -> out: [N][K] bf16 row-major
__global__ void transpose_cvt_kernel(const float* __restrict__ in,
                                     unsigned short* __restrict__ out, int K, int N) {
  __shared__ unsigned short tile[32][33];
  int tx = threadIdx.x & 31, ty = threadIdx.x >> 5;
  int n0 = blockIdx.x * 32, k0 = blockIdx.y * 32;
#pragma unroll
  for (int i = 0; i < 32; i += 8)
    tile[ty + i][tx] = f2bf(in[(size_t)(k0 + ty + i) * N + n0 + tx]);
  __syncthreads();
#pragma unroll
  for (int i = 0; i < 32; i += 8)
    out[(size_t)(n0 + ty + i) * K + k0 + tx] = tile[tx][ty + i];
}

// ---------------- GEMM: C[m][n] = sum_k A[m][k]*Bt[n][k] + bias[n] ----------------
// BM x 128 tile, BK=32, 512 thr = 8 waves (wm=wid>>2 in {0,1}: BM/2 rows; wn=wid&3:
// 32 cols). acc[BM/32][2]. A 2-slot + B 2-slot; stage(t+1) at loop top (lands under
// compute); vmcnt(0)+barrier at end (drain covered by co-resident blocks).
template <int OUT_F32, int BM>
__global__ __launch_bounds__(512, 2) void gemm_bt_kernel(
    const unsigned short* __restrict__ A, const unsigned short* __restrict__ Bt,
    const float* __restrict__ bias, void* __restrict__ Cv, int M, int N, int K) {
  constexpr int WR = BM / 2;    // rows per wave (128 or 64)
  constexpr int MF = WR / 16;   // m-frags per wave (8 or 4)
  constexpr int NA = BM / 128;  // A glds per stage (2 or 1)
  __shared__ unsigned short sA[2][BM * 32];   // 32KB (BM=256) / 16KB (BM=128)
  __shared__ unsigned short sB[2][128 * 32];  // 16KB
  int tid = threadIdx.x;
  int lane = tid & 63, wid = tid >> 6;
  int g = lane >> 4, r16 = lane & 15;

  // XCD-bijective remap (grid counts divisible by 8)
  int gx = gridDim.x;
  int d = blockIdx.y * gx + blockIdx.x;
  int cpx = (gx * gridDim.y) >> 3;
  int nid = (d & 7) * cpx + (d >> 3);
  int m0 = (nid / gx) * BM, n0 = (nid % gx) * 128;

  int wm = wid >> 2, wn = wid & 3;
  f32x4 acc[MF][2] = {};

  int srow = tid >> 2, scol = (tid & 3) * 8;   // srow 0..127
  const unsigned short* Ap0 = A + (size_t)(m0 + srow) * K + scol;
  const unsigned short* Ap1 = A + (size_t)(m0 + 128 + srow) * K + scol;  // BM=256 only
  const unsigned short* Bp = Bt + (size_t)(n0 + srow) * K + scol;

  auto STAGE = [&](int slot, int kt) {  // NA+1 glds/thread
    glds16(Ap0 + kt * 32, &sA[slot][tid * 8]);
    if constexpr (NA == 2) glds16(Ap1 + kt * 32, &sA[slot][4096 + tid * 8]);
    glds16(Bp + kt * 32, &sB[slot][tid * 8]);
  };

  int nt = K >> 5;  // K/32 >= 2
  STAGE(0, 0);
  asm volatile("s_waitcnt vmcnt(0)" ::: "memory");
  __builtin_amdgcn_s_barrier();

  int cur = 0;
#pragma unroll 1
  for (int t = 0; t < nt; ++t) {
    if (t + 1 < nt) STAGE(cur ^ 1, t + 1);  // issue early: lands under compute
    const unsigned short* a = sA[cur];
    const unsigned short* bb = sB[cur];
    // ---- phase 1: mf 0..MF/2-1 ----
    bf16x8 af[MF / 2], bfr[2];
#pragma unroll
    for (int mf = 0; mf < MF / 2; ++mf)
      af[mf] = *(const bf16x8*)&a[(wm * WR + mf * 16 + r16) * 32 + g * 8];
#pragma unroll
    for (int nf = 0; nf < 2; ++nf)
      bfr[nf] = *(const bf16x8*)&bb[(wn * 32 + nf * 16 + r16) * 32 + g * 8];
    __builtin_amdgcn_s_setprio(1);
#pragma unroll
    for (int mf = 0; mf < MF / 2; ++mf)
#pragma unroll
      for (int nf = 0; nf < 2; ++nf)
        acc[mf][nf] = __builtin_amdgcn_mfma_f32_16x16x32_bf16(af[mf], bfr[nf], acc[mf][nf], 0, 0, 0);
    __builtin_amdgcn_s_setprio(0);
    // ---- phase 2: mf MF/2..MF-1 ----
    bf16x8 ag[MF / 2];
#pragma unroll
    for (int mf = 0; mf < MF / 2; ++mf)
      ag[mf] = *(const bf16x8*)&a[(wm * WR + (mf + MF / 2) * 16 + r16) * 32 + g * 8];
    __builtin_amdgcn_s_setprio(1);
#pragma unroll
    for (int mf = 0; mf < MF / 2; ++mf)
#pragma unroll
      for (int nf = 0; nf < 2; ++nf)
        acc[mf + MF / 2][nf] =
            __builtin_amdgcn_mfma_f32_16x16x32_bf16(ag[mf], bfr[nf], acc[mf + MF / 2][nf], 0, 0, 0);
    __builtin_amdgcn_s_setprio(0);
    asm volatile("s_waitcnt vmcnt(0)" ::: "memory");  // t+1 landed (issued ~1 tile ago)
    __builtin_amdgcn_s_barrier();                     // all waves done reading cur
    cur ^= 1;
  }

#pragma unroll
  for (int mf = 0; mf < MF; ++mf)
#pragma unroll
    for (int nf = 0; nf < 2; ++nf)
#pragma unroll
      for (int r = 0; r < 4; ++r) {
        int row = m0 + wm * WR + mf * 16 + g * 4 + r;
        int col = n0 + wn * 32 + nf * 16 + r16;
        float v = acc[mf][nf][r] + bias[col];
        if (OUT_F32)
          ((float*)Cv)[(size_t)row * N + col] = v;
        else
          ((unsigned short*)Cv)[(size_t)row * N + col] = f2bf(v);
      }
}

// ---------------- V transpose: qkv[:, 2048+h*64+d] -> vT[(bh*64+d)][t] ----------------
__global__ void transpose_v_kernel(const unsigned short* __restrict__ qkv,
                                   unsigned short* __restrict__ vT) {
  __shared__ unsigned short tl[64][80];
  int t0 = blockIdx.x * 64;
  int bh = blockIdx.y, b = bh >> 4, h = bh & 15;
  int tid = threadIdx.x;
  int row = tid >> 2, c0 = (tid & 3) * 16;
  const unsigned short* src =
      qkv + (size_t)(b * 2048 + t0 + row) * 3072 + 2048 + h * 64 + c0;
  short8v a0 = *(const short8v*)src;
  short8v a1 = *(const short8v*)(src + 8);
#pragma unroll
  for (int j = 0; j < 8; ++j) tl[c0 + j][row] = (unsigned short)a0[j];
#pragma unroll
  for (int j = 0; j < 8; ++j) tl[c0 + 8 + j][row] = (unsigned short)a1[j];
  __syncthreads();
  int dd = tid >> 2, tc = (tid & 3) * 16;
  unsigned short* dst = vT + (size_t)(bh * 64 + dd) * 2048 + t0 + tc;
  *(short8v*)dst = *(const short8v*)&tl[dd][tc];
  *(short8v*)(dst + 8) = *(const short8v*)&tl[dd][tc + 8];
}

// ---------------- flash attention (swapped-QK, bf16-direct exp2) ----------------
// identical math to R12-R20 (validated). qt remap for uniform per-CU pairing.
__global__ __launch_bounds__(512, 4) void attn_kernel(
    const unsigned short* __restrict__ qkv, const unsigned short* __restrict__ vT,
    unsigned short* __restrict__ ao) {
  __shared__ unsigned short sK[2][4096];   // [buf][64x64] K tile  [kv][d]
  __shared__ unsigned short sV[2][4096];   // [buf][64x64] V^T tile [d][kv]
  __shared__ float lbuf[8][32];            // per-wave row sums
  const int T = 2048, C3 = 3072;
  const float K1 = 23.083120654223415f;    // 128 * 0.125 * log2(e)
  const float K2 = 16158.66f;              // 128*(127-4*SCL) - center + trunc-comp
  int x = blockIdx.x;                      // 0..511
  int xcd = x & 7, rest = x >> 3;          // rest 0..63
  int bh = xcd * 8 + (rest & 7);
  int j = rest >> 3;                       // 0..7
  int qt = (j < 4) ? (7 - j) : (j - 4);    // uniform pairing: (7,0),(6,1),(5,2),(4,3)
  int b = bh >> 4, h = bh & 15;
  int tid = threadIdx.x, lane = tid & 63, w = tid >> 6;  // w 0..7
  int l31 = lane & 31, hi = lane >> 5;

  int c = tid;
  int row = c >> 3, oct = (c & 7) ^ (row & 7);
  const unsigned short* Kb = qkv + (size_t)(b * T + row) * C3 + 1024 + h * 64 + oct * 8;
  const unsigned short* Vb = vT + (size_t)(bh * 64 + row) * 2048 + oct * 8;

  auto STAGE = [&](int buf, int kt) {
    int kv0 = kt * 64;
    glds16(Kb + (size_t)kv0 * C3, &sK[buf][c * 8]);
    glds16(Vb + kv0, &sV[buf][c * 8]);
  };

  int wq0 = qt * 256 + w * 32;

  const unsigned short* qp = qkv + (size_t)(b * T + wq0 + l31) * C3 + h * 64;
  bf16x8 qf[4];
#pragma unroll
  for (int d0 = 0; d0 < 4; ++d0)
    qf[d0] = *(const bf16x8*)(qp + d0 * 16 + hi * 8);

  u32x4 onesw = {0x3F803F80u, 0x3F803F80u, 0x3F803F80u, 0x3F803F80u};
  bf16x8 vones = __builtin_bit_cast(bf16x8, onesw);

  f32x16 o[2] = {};
  f32x16 lacc = {};

  int nkv = 4 * qt + 4;
  STAGE(0, 0);
  __syncthreads();
  int cur = 0;
#pragma unroll 1
  for (int kt = 0; kt < nkv; ++kt) {
    if (kt + 1 < nkv) STAGE(cur ^ 1, kt + 1);
    int kv0 = kt * 64;
    if (kv0 <= wq0 + 31) {
      // ---- S[kv][q] = K Q^T ----
      f32x16 s[2] = {};
      __builtin_amdgcn_s_setprio(1);
#pragma unroll
      for (int d0 = 0; d0 < 4; ++d0) {
        int oc2 = ((d0 * 2 + hi) ^ (l31 & 7)) * 8;
        bf16x8 kf0 = *(const bf16x8*)&sK[cur][l31 * 64 + oc2];
        bf16x8 kf1 = *(const bf16x8*)&sK[cur][(32 + l31) * 64 + oc2];
        s[0] = __builtin_amdgcn_mfma_f32_32x32x16_bf16(kf0, qf[d0], s[0], 0, 0, 0);
        s[1] = __builtin_amdgcn_mfma_f32_32x32x16_bf16(kf1, qf[d0], s[1], 0, 0, 0);
      }
      __builtin_amdgcn_s_setprio(0);

      // ---- mask (diag tiles only) ----
      if (kv0 + 63 > wq0) {
        int thr = wq0 + l31 - kv0 - 4 * hi;
#pragma unroll
        for (int sub = 0; sub < 2; ++sub)
#pragma unroll
          for (int r = 0; r < 16; ++r) {
            int cc = sub * 32 + (r & 3) + 8 * (r >> 2);
            s[sub][r] = (cc <= thr) ? s[sub][r] : -3e38f;
          }
      }

      // ---- P(bf16 bits) = linear exp2 ----
      int pb[2][16];
#pragma unroll
      for (int sub = 0; sub < 2; ++sub)
#pragma unroll
        for (int r = 0; r < 16; ++r)
          pb[sub][r] = (int)fmaxf(fmaf(s[sub][r], K1, K2), 0.0f);

      unsigned int pk[2][8];
#pragma unroll
      for (int sub = 0; sub < 2; ++sub)
#pragma unroll
        for (int i = 0; i < 8; ++i)
          pk[sub][i] = __builtin_amdgcn_perm((unsigned)pb[sub][2 * i + 1],
                                             (unsigned)pb[sub][2 * i], 0x05040100u);
      unsigned int rc[2][4];
#pragma unroll
      for (int sub = 0; sub < 2; ++sub) {
        unsigned int s0 = hi ? pk[sub][0] : pk[sub][2];
        unsigned int s1 = hi ? pk[sub][1] : pk[sub][3];
        unsigned int s2 = hi ? pk[sub][4] : pk[sub][6];
        unsigned int s3 = hi ? pk[sub][5] : pk[sub][7];
        rc[sub][0] = __shfl_xor(s0, 32, 64);
        rc[sub][1] = __shfl_xor(s1, 32, 64);
        rc[sub][2] = __shfl_xor(s2, 32, 64);
        rc[sub][3] = __shfl_xor(s3, 32, 64);
      }

      // ---- O += P V ; l += P 1 ----
      __builtin_amdgcn_s_setprio(1);
#pragma unroll
      for (int sub = 0; sub < 2; ++sub)
#pragma unroll
        for (int t = 0; t < 2; ++t) {
          u32x4 av;
          av.x = hi ? rc[sub][2 * t]     : pk[sub][4 * t];
          av.y = hi ? rc[sub][2 * t + 1] : pk[sub][4 * t + 1];
          av.z = hi ? pk[sub][4 * t + 2] : rc[sub][2 * t];
          av.w = hi ? pk[sub][4 * t + 3] : rc[sub][2 * t + 1];
          bf16x8 pa = __builtin_bit_cast(bf16x8, av);
          int kvs = sub * 2 + t;
          int ocv = ((kvs * 2 + hi) ^ (l31 & 7)) * 8;
          bf16x8 vf0 = *(const bf16x8*)&sV[cur][l31 * 64 + ocv];
          bf16x8 vf1 = *(const bf16x8*)&sV[cur][(32 + l31) * 64 + ocv];
          o[0] = __builtin_amdgcn_mfma_f32_32x32x16_bf16(pa, vf0, o[0], 0, 0, 0);
          o[1] = __builtin_amdgcn_mfma_f32_32x32x16_bf16(pa, vf1, o[1], 0, 0, 0);
          lacc = __builtin_amdgcn_mfma_f32_32x32x16_bf16(pa, vones, lacc, 0, 0, 0);
        }
      __builtin_amdgcn_s_setprio(0);
    }
    __syncthreads();
    cur ^= 1;
  }

  if (l31 == 0) {
#pragma unroll
    for (int r = 0; r < 16; ++r)
      lbuf[w][(r & 3) + 8 * (r >> 2) + 4 * hi] = lacc[r];
  }
  __syncthreads();
  float inv = 1.f / lbuf[w][l31];
#pragma unroll
  for (int r = 0; r < 16; ++r) {
    int qrow = (r & 3) + 8 * (r >> 2) + 4 * hi;
    float iv = __shfl(inv, qrow, 64);
    size_t base = (size_t)(b * T + wq0 + qrow) * 1024 + h * 64 + l31;
    ao[base] = f2bf(o[0][r] * iv);
    ao[base + 32] = f2bf(o[1][r] * iv);
  }
}

// ---------------- launch ----------------
extern "C" void kernel_launch(void* const* d_in, const int* in_sizes, int n_in,
                              void* d_out, int out_size, void* d_ws, size_t ws_size,
                              hipStream_t stream) {
  const float* x      = (const float*)d_in[0];
  const float* w_qkv  = (const float*)d_in[1];
  const float* b_qkv  = (const float*)d_in[2];
  const float* w_proj = (const float*)d_in[3];
  const float* b_proj = (const float*)d_in[4];
  float* out = (float*)d_out;

  char* ws = (char*)d_ws;
  unsigned short* xb     = (unsigned short*)(ws);
  unsigned short* ao     = (unsigned short*)(ws);             // alias: xb dead after GEMM1
  unsigned short* wqkvT  = (unsigned short*)(ws + (16u << 20));
  unsigned short* wprojT = (unsigned short*)(ws + (22u << 20));
  unsigned short* qkv    = (unsigned short*)(ws + (24u << 20));
  unsigned short* vT     = (unsigned short*)(ws + (72u << 20));

  cvt_f32_bf16_kernel<<<2048, 256, 0, stream>>>(x, xb, 8192 * 1024);
  transpose_cvt_kernel<<<dim3(3072 / 32, 1024 / 32), 256, 0, stream>>>(w_qkv, wqkvT, 1024, 3072);
  transpose_cvt_kernel<<<dim3(1024 / 32, 1024 / 32), 256, 0, stream>>>(w_proj, wprojT, 1024, 1024);

  gemm_bt_kernel<0, 256><<<dim3(3072 / 128, 8192 / 256), 512, 0, stream>>>(
      xb, wqkvT, b_qkv, (void*)qkv, 8192, 3072, 1024);

  transpose_v_kernel<<<dim3(32, 64), 256, 0, stream>>>(qkv, vT);

  attn_kernel<<<dim3(512), 512, 0, stream>>>(qkv, vT, ao);

  gemm_bt_kernel<1, 128><<<dim3(1024 / 128, 8192 / 128), 512, 0, stream>>>(
      ao, wprojT, b_proj, (void*)out, 8192, 1024, 1024);
}

// Round 22
// 171.964 us; speedup vs baseline: 1.0257x; 1.0257x over previous
//
#include <hip/hip_runtime.h>
#include <hip/hip_bf16.h>

// B=4 T=2048 C=1024 H=16 hd=64, causal MHSA, f32 in/out, bf16 MFMA internally.
// Pipeline: cvt(x) / transpose-cvt(w) -> GEMM1 (qkv) -> transpose V -> flash attn -> GEMM2.
// Attn: swapped-QK, static-max softmax, bf16-direct exp2, l via ones-MFMA (validated).
// R22: restore R20 exactly (session best, 172.35us): GEMM = R15 3-slot-A + 2-slot-B
//      counted-vmcnt(NA) pipeline, bounds (512,2); BM=256 GEMM1 / BM=128 GEMM2.
//      R21's 2-slot/48KB variant did NOT raise residency (occupancy stayed 30%) and
//      lost staging depth (-5us) -> reverted. GEMM plateau documented at ~77us.

typedef float f32x4 __attribute__((ext_vector_type(4)));
typedef float f32x16 __attribute__((ext_vector_type(16)));
typedef __bf16 bf16x8 __attribute__((ext_vector_type(8)));
typedef short short8v __attribute__((ext_vector_type(8)));
typedef unsigned int u32x4 __attribute__((ext_vector_type(4)));

__device__ __forceinline__ unsigned short f2bf(float f) {
  __hip_bfloat16 h = __float2bfloat16(f);
  return __builtin_bit_cast(unsigned short, h);
}

__device__ __forceinline__ void glds16(const void* g, void* l) {
  __builtin_amdgcn_global_load_lds((const __attribute__((address_space(1))) void*)g,
                                   (__attribute__((address_space(3))) void*)l, 16, 0, 0);
}

template <int N> __device__ __forceinline__ void waitvm() {
  if constexpr (N == 0) asm volatile("s_waitcnt vmcnt(0)" ::: "memory");
  else if constexpr (N == 1) asm volatile("s_waitcnt vmcnt(1)" ::: "memory");
  else if constexpr (N == 2) asm volatile("s_waitcnt vmcnt(2)" ::: "memory");
}

// ---------------- conversions ----------------
__global__ void cvt_f32_bf16_kernel(const float* __restrict__ in,
                                    unsigned short* __restrict__ out, int n) {
  int stride = gridDim.x * blockDim.x * 4;
  for (int i = (blockIdx.x * blockDim.x + threadIdx.x) * 4; i < n; i += stride) {
    float4 v = *(const float4*)(in + i);
    ushort4 o;
    o.x = f2bf(v.x); o.y = f2bf(v.y); o.z = f2bf(v.z); o.w = f2bf(v.w);
    *(ushort4*)(out + i) = o;
  }
}

// in: [K][N] f32 row-major -> out: [N][K] bf16 row-major
__global__ void transpose_cvt_kernel(const float* __restrict__ in,
                                     unsigned short* __restrict__ out, int K, int N) {
  __shared__ unsigned short tile[32][33];
  int tx = threadIdx.x & 31, ty = threadIdx.x >> 5;
  int n0 = blockIdx.x * 32, k0 = blockIdx.y * 32;
#pragma unroll
  for (int i = 0; i < 32; i += 8)
    tile[ty + i][tx] = f2bf(in[(size_t)(k0 + ty + i) * N + n0 + tx]);
  __syncthreads();
#pragma unroll
  for (int i = 0; i < 32; i += 8)
    out[(size_t)(n0 + ty + i) * K + k0 + tx] = tile[tx][ty + i];
}

// ---------------- GEMM: C[m][n] = sum_k A[m][k]*Bt[n][k] + bias[n] ----------------
// BM x 128 tile, BK=32, 512 thr = 8 waves (wm=wid>>2 in {0,1}: BM/2 rows; wn=wid&3:
// 32 cols). acc[BM/32][2]. A 3-slot staged 2 ahead (NA=BM/128 glds/stage), B 2-slot
// staged 1 ahead (issued BEFORE A so end-of-tile vmcnt(NA) covers B(t+1)+A(t+1)).
template <int OUT_F32, int BM>
__global__ __launch_bounds__(512, 2) void gemm_bt_kernel(
    const unsigned short* __restrict__ A, const unsigned short* __restrict__ Bt,
    const float* __restrict__ bias, void* __restrict__ Cv, int M, int N, int K) {
  constexpr int WR = BM / 2;    // rows per wave (128 or 64)
  constexpr int MF = WR / 16;   // m-frags per wave (8 or 4)
  constexpr int NA = BM / 128;  // A glds per stage (2 or 1)
  __shared__ unsigned short sA[3][BM * 32];   // staged 2 ahead
  __shared__ unsigned short sB[2][128 * 32];  // staged 1 ahead
  int tid = threadIdx.x;
  int lane = tid & 63, wid = tid >> 6;
  int g = lane >> 4, r16 = lane & 15;

  // XCD-bijective remap (grid counts divisible by 8)
  int gx = gridDim.x;
  int d = blockIdx.y * gx + blockIdx.x;
  int cpx = (gx * gridDim.y) >> 3;
  int nid = (d & 7) * cpx + (d >> 3);
  int m0 = (nid / gx) * BM, n0 = (nid % gx) * 128;

  int wm = wid >> 2, wn = wid & 3;
  f32x4 acc[MF][2] = {};

  int srow = tid >> 2, scol = (tid & 3) * 8;   // srow 0..127
  const unsigned short* Ap0 = A + (size_t)(m0 + srow) * K + scol;
  const unsigned short* Ap1 = A + (size_t)(m0 + 128 + srow) * K + scol;  // BM=256 only
  const unsigned short* Bp = Bt + (size_t)(n0 + srow) * K + scol;

  auto STAGE_A = [&](int slot, int kt) {  // NA glds/thread
    glds16(Ap0 + kt * 32, &sA[slot][tid * 8]);
    if constexpr (NA == 2) glds16(Ap1 + kt * 32, &sA[slot][4096 + tid * 8]);
  };
  auto STAGE_B = [&](int slot, int kt) {  // 1 glds/thread
    glds16(Bp + kt * 32, &sB[slot][tid * 8]);
  };

  int nt = K >> 5;  // K/32 >= 2
  STAGE_A(0, 0);
  STAGE_B(0, 0);
  STAGE_A(1, 1);
  waitvm<NA>();                    // A(1) may stay in flight; A(0),B(0) landed
  __builtin_amdgcn_s_barrier();

  int slA = 0;
#pragma unroll 1
  for (int t = 0; t < nt; ++t) {
    const unsigned short* a = sA[slA];
    const unsigned short* bb = sB[t & 1];
    // ---- phase 1: mf 0..MF/2-1 ----
    bf16x8 af[MF / 2], bfr[2];
#pragma unroll
    for (int mf = 0; mf < MF / 2; ++mf)
      af[mf] = *(const bf16x8*)&a[(wm * WR + mf * 16 + r16) * 32 + g * 8];
#pragma unroll
    for (int nf = 0; nf < 2; ++nf)
      bfr[nf] = *(const bf16x8*)&bb[(wn * 32 + nf * 16 + r16) * 32 + g * 8];
    if (t + 1 < nt) STAGE_B((t + 1) & 1, t + 1);   // issued BEFORE A(t+2)
    __builtin_amdgcn_s_barrier();
    __builtin_amdgcn_s_setprio(1);
#pragma unroll
    for (int mf = 0; mf < MF / 2; ++mf)
#pragma unroll
      for (int nf = 0; nf < 2; ++nf)
        acc[mf][nf] = __builtin_amdgcn_mfma_f32_16x16x32_bf16(af[mf], bfr[nf], acc[mf][nf], 0, 0, 0);
    __builtin_amdgcn_s_setprio(0);
    // ---- phase 2: mf MF/2..MF-1 ----
    bf16x8 ag[MF / 2];
#pragma unroll
    for (int mf = 0; mf < MF / 2; ++mf)
      ag[mf] = *(const bf16x8*)&a[(wm * WR + (mf + MF / 2) * 16 + r16) * 32 + g * 8];
    if (t + 2 < nt) {
      int ns = slA + 2; if (ns >= 3) ns -= 3;
      STAGE_A(ns, t + 2);
      waitvm<NA>();                // A(t+2) in flight; B(t+1)+A(t+1) landed
    } else {
      waitvm<0>();
    }
    __builtin_amdgcn_s_barrier();
    __builtin_amdgcn_s_setprio(1);
#pragma unroll
    for (int mf = 0; mf < MF / 2; ++mf)
#pragma unroll
      for (int nf = 0; nf < 2; ++nf)
        acc[mf + MF / 2][nf] =
            __builtin_amdgcn_mfma_f32_16x16x32_bf16(ag[mf], bfr[nf], acc[mf + MF / 2][nf], 0, 0, 0);
    __builtin_amdgcn_s_setprio(0);
    slA = slA == 2 ? 0 : slA + 1;
  }

#pragma unroll
  for (int mf = 0; mf < MF; ++mf)
#pragma unroll
    for (int nf = 0; nf < 2; ++nf)
#pragma unroll
      for (int r = 0; r < 4; ++r) {
        int row = m0 + wm * WR + mf * 16 + g * 4 + r;
        int col = n0 + wn * 32 + nf * 16 + r16;
        float v = acc[mf][nf][r] + bias[col];
        if (OUT_F32)
          ((float*)Cv)[(size_t)row * N + col] = v;
        else
          ((unsigned short*)Cv)[(size_t)row * N + col] = f2bf(v);
      }
}

// ---------------- V transpose: qkv[:, 2048+h*64+d] -> vT[(bh*64+d)][t] ----------------
__global__ void transpose_v_kernel(const unsigned short* __restrict__ qkv,
                                   unsigned short* __restrict__ vT) {
  __shared__ unsigned short tl[64][80];
  int t0 = blockIdx.x * 64;
  int bh = blockIdx.y, b = bh >> 4, h = bh & 15;
  int tid = threadIdx.x;
  int row = tid >> 2, c0 = (tid & 3) * 16;
  const unsigned short* src =
      qkv + (size_t)(b * 2048 + t0 + row) * 3072 + 2048 + h * 64 + c0;
  short8v a0 = *(const short8v*)src;
  short8v a1 = *(const short8v*)(src + 8);
#pragma unroll
  for (int j = 0; j < 8; ++j) tl[c0 + j][row] = (unsigned short)a0[j];
#pragma unroll
  for (int j = 0; j < 8; ++j) tl[c0 + 8 + j][row] = (unsigned short)a1[j];
  __syncthreads();
  int dd = tid >> 2, tc = (tid & 3) * 16;
  unsigned short* dst = vT + (size_t)(bh * 64 + dd) * 2048 + t0 + tc;
  *(short8v*)dst = *(const short8v*)&tl[dd][tc];
  *(short8v*)(dst + 8) = *(const short8v*)&tl[dd][tc + 8];
}

// ---------------- flash attention (swapped-QK, bf16-direct exp2) ----------------
// identical math to R12-R20 (validated). qt remap for uniform per-CU pairing.
__global__ __launch_bounds__(512, 4) void attn_kernel(
    const unsigned short* __restrict__ qkv, const unsigned short* __restrict__ vT,
    unsigned short* __restrict__ ao) {
  __shared__ unsigned short sK[2][4096];   // [buf][64x64] K tile  [kv][d]
  __shared__ unsigned short sV[2][4096];   // [buf][64x64] V^T tile [d][kv]
  __shared__ float lbuf[8][32];            // per-wave row sums
  const int T = 2048, C3 = 3072;
  const float K1 = 23.083120654223415f;    // 128 * 0.125 * log2(e)
  const float K2 = 16158.66f;              // 128*(127-4*SCL) - center + trunc-comp
  int x = blockIdx.x;                      // 0..511
  int xcd = x & 7, rest = x >> 3;          // rest 0..63
  int bh = xcd * 8 + (rest & 7);
  int j = rest >> 3;                       // 0..7
  int qt = (j < 4) ? (7 - j) : (j - 4);    // uniform pairing: (7,0),(6,1),(5,2),(4,3)
  int b = bh >> 4, h = bh & 15;
  int tid = threadIdx.x, lane = tid & 63, w = tid >> 6;  // w 0..7
  int l31 = lane & 31, hi = lane >> 5;

  int c = tid;
  int row = c >> 3, oct = (c & 7) ^ (row & 7);
  const unsigned short* Kb = qkv + (size_t)(b * T + row) * C3 + 1024 + h * 64 + oct * 8;
  const unsigned short* Vb = vT + (size_t)(bh * 64 + row) * 2048 + oct * 8;

  auto STAGE = [&](int buf, int kt) {
    int kv0 = kt * 64;
    glds16(Kb + (size_t)kv0 * C3, &sK[buf][c * 8]);
    glds16(Vb + kv0, &sV[buf][c * 8]);
  };

  int wq0 = qt * 256 + w * 32;

  const unsigned short* qp = qkv + (size_t)(b * T + wq0 + l31) * C3 + h * 64;
  bf16x8 qf[4];
#pragma unroll
  for (int d0 = 0; d0 < 4; ++d0)
    qf[d0] = *(const bf16x8*)(qp + d0 * 16 + hi * 8);

  u32x4 onesw = {0x3F803F80u, 0x3F803F80u, 0x3F803F80u, 0x3F803F80u};
  bf16x8 vones = __builtin_bit_cast(bf16x8, onesw);

  f32x16 o[2] = {};
  f32x16 lacc = {};

  int nkv = 4 * qt + 4;
  STAGE(0, 0);
  __syncthreads();
  int cur = 0;
#pragma unroll 1
  for (int kt = 0; kt < nkv; ++kt) {
    if (kt + 1 < nkv) STAGE(cur ^ 1, kt + 1);
    int kv0 = kt * 64;
    if (kv0 <= wq0 + 31) {
      // ---- S[kv][q] = K Q^T ----
      f32x16 s[2] = {};
      __builtin_amdgcn_s_setprio(1);
#pragma unroll
      for (int d0 = 0; d0 < 4; ++d0) {
        int oc2 = ((d0 * 2 + hi) ^ (l31 & 7)) * 8;
        bf16x8 kf0 = *(const bf16x8*)&sK[cur][l31 * 64 + oc2];
        bf16x8 kf1 = *(const bf16x8*)&sK[cur][(32 + l31) * 64 + oc2];
        s[0] = __builtin_amdgcn_mfma_f32_32x32x16_bf16(kf0, qf[d0], s[0], 0, 0, 0);
        s[1] = __builtin_amdgcn_mfma_f32_32x32x16_bf16(kf1, qf[d0], s[1], 0, 0, 0);
      }
      __builtin_amdgcn_s_setprio(0);

      // ---- mask (diag tiles only) ----
      if (kv0 + 63 > wq0) {
        int thr = wq0 + l31 - kv0 - 4 * hi;
#pragma unroll
        for (int sub = 0; sub < 2; ++sub)
#pragma unroll
          for (int r = 0; r < 16; ++r) {
            int cc = sub * 32 + (r & 3) + 8 * (r >> 2);
            s[sub][r] = (cc <= thr) ? s[sub][r] : -3e38f;
          }
      }

      // ---- P(bf16 bits) = linear exp2 ----
      int pb[2][16];
#pragma unroll
      for (int sub = 0; sub < 2; ++sub)
#pragma unroll
        for (int r = 0; r < 16; ++r)
          pb[sub][r] = (int)fmaxf(fmaf(s[sub][r], K1, K2), 0.0f);

      unsigned int pk[2][8];
#pragma unroll
      for (int sub = 0; sub < 2; ++sub)
#pragma unroll
        for (int i = 0; i < 8; ++i)
          pk[sub][i] = __builtin_amdgcn_perm((unsigned)pb[sub][2 * i + 1],
                                             (unsigned)pb[sub][2 * i], 0x05040100u);
      unsigned int rc[2][4];
#pragma unroll
      for (int sub = 0; sub < 2; ++sub) {
        unsigned int s0 = hi ? pk[sub][0] : pk[sub][2];
        unsigned int s1 = hi ? pk[sub][1] : pk[sub][3];
        unsigned int s2 = hi ? pk[sub][4] : pk[sub][6];
        unsigned int s3 = hi ? pk[sub][5] : pk[sub][7];
        rc[sub][0] = __shfl_xor(s0, 32, 64);
        rc[sub][1] = __shfl_xor(s1, 32, 64);
        rc[sub][2] = __shfl_xor(s2, 32, 64);
        rc[sub][3] = __shfl_xor(s3, 32, 64);
      }

      // ---- O += P V ; l += P 1 ----
      __builtin_amdgcn_s_setprio(1);
#pragma unroll
      for (int sub = 0; sub < 2; ++sub)
#pragma unroll
        for (int t = 0; t < 2; ++t) {
          u32x4 av;
          av.x = hi ? rc[sub][2 * t]     : pk[sub][4 * t];
          av.y = hi ? rc[sub][2 * t + 1] : pk[sub][4 * t + 1];
          av.z = hi ? pk[sub][4 * t + 2] : rc[sub][2 * t];
          av.w = hi ? pk[sub][4 * t + 3] : rc[sub][2 * t + 1];
          bf16x8 pa = __builtin_bit_cast(bf16x8, av);
          int kvs = sub * 2 + t;
          int ocv = ((kvs * 2 + hi) ^ (l31 & 7)) * 8;
          bf16x8 vf0 = *(const bf16x8*)&sV[cur][l31 * 64 + ocv];
          bf16x8 vf1 = *(const bf16x8*)&sV[cur][(32 + l31) * 64 + ocv];
          o[0] = __builtin_amdgcn_mfma_f32_32x32x16_bf16(pa, vf0, o[0], 0, 0, 0);
          o[1] = __builtin_amdgcn_mfma_f32_32x32x16_bf16(pa, vf1, o[1], 0, 0, 0);
          lacc = __builtin_amdgcn_mfma_f32_32x32x16_bf16(pa, vones, lacc, 0, 0, 0);
        }
      __builtin_amdgcn_s_setprio(0);
    }
    __syncthreads();
    cur ^= 1;
  }

  if (l31 == 0) {
#pragma unroll
    for (int r = 0; r < 16; ++r)
      lbuf[w][(r & 3) + 8 * (r >> 2) + 4 * hi] = lacc[r];
  }
  __syncthreads();
  float inv = 1.f / lbuf[w][l31];
#pragma unroll
  for (int r = 0; r < 16; ++r) {
    int qrow = (r & 3) + 8 * (r >> 2) + 4 * hi;
    float iv = __shfl(inv, qrow, 64);
    size_t base = (size_t)(b * T + wq0 + qrow) * 1024 + h * 64 + l31;
    ao[base] = f2bf(o[0][r] * iv);
    ao[base + 32] = f2bf(o[1][r] * iv);
  }
}

// ---------------- launch ----------------
extern "C" void kernel_launch(void* const* d_in, const int* in_sizes, int n_in,
                              void* d_out, int out_size, void* d_ws, size_t ws_size,
                              hipStream_t stream) {
  const float* x      = (const float*)d_in[0];
  const float* w_qkv  = (const float*)d_in[1];
  const float* b_qkv  = (const float*)d_in[2];
  const float* w_proj = (const float*)d_in[3];
  const float* b_proj = (const float*)d_in[4];
  float* out = (float*)d_out;

  char* ws = (char*)d_ws;
  unsigned short* xb     = (unsigned short*)(ws);
  unsigned short* ao     = (unsigned short*)(ws);             // alias: xb dead after GEMM1
  unsigned short* wqkvT  = (unsigned short*)(ws + (16u << 20));
  unsigned short* wprojT = (unsigned short*)(ws + (22u << 20));
  unsigned short* qkv    = (unsigned short*)(ws + (24u << 20));
  unsigned short* vT     = (unsigned short*)(ws + (72u << 20));

  cvt_f32_bf16_kernel<<<2048, 256, 0, stream>>>(x, xb, 8192 * 1024);
  transpose_cvt_kernel<<<dim3(3072 / 32, 1024 / 32), 256, 0, stream>>>(w_qkv, wqkvT, 1024, 3072);
  transpose_cvt_kernel<<<dim3(1024 / 32, 1024 / 32), 256, 0, stream>>>(w_proj, wprojT, 1024, 1024);

  gemm_bt_kernel<0, 256><<<dim3(3072 / 128, 8192 / 256), 512, 0, stream>>>(
      xb, wqkvT, b_qkv, (void*)qkv, 8192, 3072, 1024);

  transpose_v_kernel<<<dim3(32, 64), 256, 0, stream>>>(qkv, vT);

  attn_kernel<<<dim3(512), 512, 0, stream>>>(qkv, vT, ao);

  gemm_bt_kernel<1, 128><<<dim3(1024 / 128, 8192 / 128), 512, 0, stream>>>(
      ao, wprojT, b_proj, (void*)out, 8192, 1024, 1024);
}